// Round 3
// baseline (822.284 us; speedup 1.0000x reference)
//
#include <hip/hip_runtime.h>

typedef __bf16 bf16_t;
typedef __bf16 bf16x8 __attribute__((ext_vector_type(8)));
typedef float f32x4 __attribute__((ext_vector_type(4)));
typedef unsigned short ushort_t;

#define MFMA_16x16x32(a, b, c) __builtin_amdgcn_mfma_f32_16x16x32_bf16((a), (b), (c), 0, 0, 0)

// NaN-squashing clamp: v_max_f32/v_min_f32 return the non-NaN operand, so a
// NaN input becomes -1e4 (a loud, finite, diagnostic value).
__device__ __forceinline__ float clampf(float v) {
  return fminf(fmaxf(v, -1e4f), 1e4f);
}

// ---------------------------------------------------------------------------
// Input-dtype detector. Reads the first 4096 16-bit halves of x. If x is f32,
// the low half of each f32 word has a uniform-random bf16-exponent field ->
// ~47% land outside [2^-69, 2^65]. True bf16 N(0,1) data: ~0%.
// ---------------------------------------------------------------------------
__global__ void detect_dtype(const ushort_t* __restrict__ x, int* __restrict__ flag) {
  __shared__ int cnt[256];
  int c = 0;
#pragma unroll
  for (int i = 0; i < 16; ++i) {
    const ushort_t u = x[threadIdx.x * 16 + i];
    const int e = (u >> 7) & 0xFF;
    if ((u & 0x7FFF) != 0 && (e < 0x3A || e > 0xC0)) ++c;
  }
  cnt[threadIdx.x] = c;
  __syncthreads();
  if (threadIdx.x == 0) {
    int t = 0;
    for (int i = 0; i < 256; ++i) t += cnt[i];
    *flag = (t > 512) ? 1 : 0;
  }
}

// ---------------------------------------------------------------------------
// Normalize an input tensor to bf16. flag==1: src is f32 (downconvert);
// flag==0: src is bf16 (plain 16B copy). n8 = element count / 8.
// ---------------------------------------------------------------------------
__global__ __launch_bounds__(256) void convert_to_bf16(const void* __restrict__ src,
                                                       bf16_t* __restrict__ dst, int n8,
                                                       const int* __restrict__ flag) {
  const int isF32 = *flag;
  int i = blockIdx.x * 256 + threadIdx.x;
  const int stride = gridDim.x * 256;
  if (isF32) {
    const float4* s = (const float4*)src;
    for (; i < n8; i += stride) {
      const float4 a = s[(size_t)i * 2];
      const float4 b = s[(size_t)i * 2 + 1];
      bf16x8 o;
      o[0] = (bf16_t)a.x; o[1] = (bf16_t)a.y; o[2] = (bf16_t)a.z; o[3] = (bf16_t)a.w;
      o[4] = (bf16_t)b.x; o[5] = (bf16_t)b.y; o[6] = (bf16_t)b.z; o[7] = (bf16_t)b.w;
      *(bf16x8*)(dst + (size_t)i * 8) = o;
    }
  } else {
    const uint4* s = (const uint4*)src;
    for (; i < n8; i += stride) ((uint4*)dst)[i] = s[i];
  }
}

// ---------------------------------------------------------------------------
// 64x64 bf16 transpose: out[c][r] = in[r][c].  R,C multiples of 64.
// ---------------------------------------------------------------------------
__global__ __launch_bounds__(256) void transpose_b16(const ushort_t* __restrict__ in,
                                                     ushort_t* __restrict__ out,
                                                     int R, int C) {
  __shared__ alignas(16) ushort_t t[64 * 72];
  const int tid = threadIdx.x;
  const int c0 = blockIdx.x * 64;
  const int r0 = blockIdx.y * 64;
#pragma unroll
  for (int it = 0; it < 2; ++it) {
    int cid = tid + it * 256;
    int row = cid >> 3, co = (cid & 7) * 8;
    *(uint4*)(t + row * 72 + co) = *(const uint4*)(in + (size_t)(r0 + row) * C + c0 + co);
  }
  __syncthreads();
#pragma unroll
  for (int it = 0; it < 2; ++it) {
    int cid = tid + it * 256;
    int orow = cid >> 3, ko = (cid & 7) * 8;
    uint4 u;
    ushort_t* tp = (ushort_t*)&u;
#pragma unroll
    for (int j = 0; j < 8; ++j) tp[j] = t[(ko + j) * 72 + orow];
    *(uint4*)(out + (size_t)(c0 + orow) * R + r0 + ko) = u;
  }
}

// ---------------------------------------------------------------------------
// GEMM: C[M][N] = A[M][K] * Bt[N][K]^T   (A has leading dim lda; Bt tight)
// 128x128 tile / workgroup, 4 waves each 64x64, BK=32, plain LDS staging.
// MODE 0: store to Cout (bf16 or f32 per *flag), leading dim N_out.
// MODE 1: QKV epilogue: cols <2048 -> qk[m][2048]; cols >=2048 -> vT[b][h][d][L].
// ---------------------------------------------------------------------------
template <int MODE>
__global__ __launch_bounds__(256) void gemm_bf16(const bf16_t* __restrict__ A, int lda,
                                                 const bf16_t* __restrict__ Bt,
                                                 void* __restrict__ Cout, int N_out,
                                                 bf16_t* __restrict__ qk,
                                                 bf16_t* __restrict__ vT,
                                                 int M, int K,
                                                 const int* __restrict__ flag) {
  __shared__ alignas(16) bf16_t a_lds[128 * 32];
  __shared__ alignas(16) bf16_t b_lds[128 * 32];
  const int tid = threadIdx.x;
  const int wave = tid >> 6;
  const int lane = tid & 63;
  const int l15 = lane & 15;
  const int quad = lane >> 4;
  const int tm = blockIdx.y * 128;
  const int tn = blockIdx.x * 128;
  const int wm = (wave >> 1) * 64;
  const int wn = (wave & 1) * 64;

  f32x4 acc[4][4];
#pragma unroll
  for (int i = 0; i < 4; ++i)
#pragma unroll
    for (int j = 0; j < 4; ++j) acc[i][j] = (f32x4){0.f, 0.f, 0.f, 0.f};

  const int srow0 = tid >> 2;
  const int scol = (tid & 3) * 8;

  for (int k0 = 0; k0 < K; k0 += 32) {
    uint4 av[2], bv[2];
#pragma unroll
    for (int it = 0; it < 2; ++it) {
      const int row = srow0 + it * 64;
      av[it] = *(const uint4*)(A + (size_t)(tm + row) * lda + k0 + scol);
      bv[it] = *(const uint4*)(Bt + (size_t)(tn + row) * K + k0 + scol);
    }
    __syncthreads();
#pragma unroll
    for (int it = 0; it < 2; ++it) {
      const int row = srow0 + it * 64;
      *(uint4*)(a_lds + row * 32 + scol) = av[it];
      *(uint4*)(b_lds + row * 32 + scol) = bv[it];
    }
    __syncthreads();

    bf16x8 af[4], bfr[4];
#pragma unroll
    for (int i = 0; i < 4; ++i)
      af[i] = *(const bf16x8*)(a_lds + (wm + i * 16 + l15) * 32 + quad * 8);
#pragma unroll
    for (int j = 0; j < 4; ++j)
      bfr[j] = *(const bf16x8*)(b_lds + (wn + j * 16 + l15) * 32 + quad * 8);
#pragma unroll
    for (int i = 0; i < 4; ++i)
#pragma unroll
      for (int j = 0; j < 4; ++j) acc[i][j] = MFMA_16x16x32(af[i], bfr[j], acc[i][j]);
  }

  if (MODE == 0) {
    const int isF32 = *flag;
#pragma unroll
    for (int i = 0; i < 4; ++i) {
      const int m = tm + wm + i * 16 + quad * 4;
#pragma unroll
      for (int j = 0; j < 4; ++j) {
        const int n = tn + wn + j * 16 + l15;
        if (isF32) {
          float* cp = (float*)Cout + (size_t)m * N_out + n;
#pragma unroll
          for (int r = 0; r < 4; ++r) cp[(size_t)r * N_out] = clampf(acc[i][j][r]);
        } else {
          bf16_t* cp = (bf16_t*)Cout + (size_t)m * N_out + n;
#pragma unroll
          for (int r = 0; r < 4; ++r) cp[(size_t)r * N_out] = (bf16_t)clampf(acc[i][j][r]);
        }
      }
    }
  } else {
#pragma unroll
    for (int i = 0; i < 4; ++i) {
      const int m = tm + wm + i * 16 + quad * 4;
      const int b = m >> 12;
      const int l = m & 4095;
#pragma unroll
      for (int j = 0; j < 4; ++j) {
        const int n = tn + wn + j * 16 + l15;
        if (n < 2048) {
          bf16_t* p = qk + (size_t)m * 2048 + n;
#pragma unroll
          for (int r = 0; r < 4; ++r) p[(size_t)r * 2048] = (bf16_t)clampf(acc[i][j][r]);
        } else {
          const int np = n - 2048;
          const int hh = np >> 6, dd = np & 63;
          bf16_t* p = vT + (((size_t)b * 16 + hh) * 64 + dd) * 4096 + l;
#pragma unroll
          for (int r = 0; r < 4; ++r) p[r] = (bf16_t)clampf(acc[i][j][r]);
        }
      }
    }
  }
}

// ---------------------------------------------------------------------------
// Sliding-window attention. One workgroup = 64 queries of one (b,h); 4 waves x
// 16 rows. Window = 5 chunks of 64 keys. qk: [b*4096+pos][2048] (Q at col h*64,
// K at col 1024+h*64). vT: [b][h][d][4096]. Output O overwrites the Q columns
// of qk (only the owning workgroup ever reads them, and it reads Q at entry).
// ---------------------------------------------------------------------------
__global__ __launch_bounds__(256) void attn_swa(bf16_t* qk, const bf16_t* __restrict__ vT) {
  __shared__ alignas(16) bf16_t k_lds[64 * 72];   // [key][d]
  __shared__ alignas(16) bf16_t vt_lds[64 * 72];  // [d][key]
  __shared__ alignas(16) bf16_t p_lds[4 * 16 * 72];

  const int wg = blockIdx.x;
  const int b = wg >> 10;
  const int h = (wg >> 6) & 15;
  const int qt = wg & 63;
  const int blk = qt >> 2;
  const int wq = qt & 3;
  const int tid = threadIdx.x;
  const int wave = tid >> 6;
  const int lane = tid & 63;
  const int l15 = lane & 15;
  const int quad = lane >> 4;
  const int qw = qt * 64 + wave * 16;  // this wave's absolute query base

  // Q fragments (A-operand: m=lane&15 row, k = quad*8+j, two 32-d chunks)
  const size_t qoff = ((size_t)(b * 4096 + qw + l15)) * 2048 + h * 64;
  const bf16x8 qf0 = *(const bf16x8*)(qk + qoff + quad * 8);
  const bf16x8 qf1 = *(const bf16x8*)(qk + qoff + 32 + quad * 8);

  f32x4 of[4];
#pragma unroll
  for (int i = 0; i < 4; ++i) of[i] = (f32x4){0.f, 0.f, 0.f, 0.f};
  float m_i[4], l_i[4];
#pragma unroll
  for (int r = 0; r < 4; ++r) {
    m_i[r] = -1e30f;
    l_i[r] = 0.0f;
  }

  const int kb0 = blk * 256 - 256;
  const int kclo = (blk == 0) ? 4 : wq;
  const int kchi = wq + 4;

  for (int kc = kclo; kc <= kchi; ++kc) {
    const int kb = kb0 + kc * 64;
    __syncthreads();  // prior iteration's LDS reads done
#pragma unroll
    for (int it = 0; it < 2; ++it) {
      int cid = tid + it * 256;
      int row = cid >> 3;
      int co = (cid & 7) * 8;
      *(uint4*)(k_lds + row * 72 + co) =
          *(const uint4*)(qk + ((size_t)(b * 4096 + kb + row)) * 2048 + 1024 + h * 64 + co);
      *(uint4*)(vt_lds + row * 72 + co) =
          *(const uint4*)(vT + (((size_t)b * 16 + h) * 64 + row) * 4096 + kb + co);
    }
    __syncthreads();

    // S = Q K^T  (16 queries x 64 keys)
    f32x4 s[4];
#pragma unroll
    for (int nt = 0; nt < 4; ++nt) {
      bf16x8 kf0 = *(const bf16x8*)(k_lds + (nt * 16 + l15) * 72 + quad * 8);
      bf16x8 kf1 = *(const bf16x8*)(k_lds + (nt * 16 + l15) * 72 + 32 + quad * 8);
      f32x4 z = (f32x4){0.f, 0.f, 0.f, 0.f};
      z = MFMA_16x16x32(qf0, kf0, z);
      z = MFMA_16x16x32(qf1, kf1, z);
      s[nt] = z;
    }

    // mask + scale; NaN-squash via fmaxf/fminf (NaN -> masked)
    float sv[4][4];
#pragma unroll
    for (int nt = 0; nt < 4; ++nt) {
      const int key = kb + nt * 16 + l15;
#pragma unroll
      for (int r = 0; r < 4; ++r) {
        const int p = qw + quad * 4 + r;
        const bool valid = (key <= p) && (key + 256 > p);
        sv[nt][r] = valid ? fminf(fmaxf(s[nt][r] * 0.125f, -1e30f), 1e4f) : -1e30f;
      }
    }
    float rm[4];
#pragma unroll
    for (int r = 0; r < 4; ++r)
      rm[r] = fmaxf(fmaxf(sv[0][r], sv[1][r]), fmaxf(sv[2][r], sv[3][r]));
#pragma unroll
    for (int off = 1; off < 16; off <<= 1)
#pragma unroll
      for (int r = 0; r < 4; ++r) rm[r] = fmaxf(rm[r], __shfl_xor(rm[r], off));

    float mn[4], alpha[4];
#pragma unroll
    for (int r = 0; r < 4; ++r) {
      mn[r] = fmaxf(m_i[r], rm[r]);
      alpha[r] = __expf(m_i[r] - mn[r]);
      m_i[r] = mn[r];
    }

    float rs[4] = {0.f, 0.f, 0.f, 0.f};
#pragma unroll
    for (int nt = 0; nt < 4; ++nt)
#pragma unroll
      for (int r = 0; r < 4; ++r) {
        const float pv = (sv[nt][r] > -1e29f) ? __expf(sv[nt][r] - mn[r]) : 0.0f;
        rs[r] += pv;
        p_lds[wave * 1152 + (quad * 4 + r) * 72 + nt * 16 + l15] = (bf16_t)pv;
      }
#pragma unroll
    for (int off = 1; off < 16; off <<= 1)
#pragma unroll
      for (int r = 0; r < 4; ++r) rs[r] += __shfl_xor(rs[r], off);
#pragma unroll
    for (int r = 0; r < 4; ++r) l_i[r] = l_i[r] * alpha[r] + rs[r];
#pragma unroll
    for (int dt = 0; dt < 4; ++dt)
#pragma unroll
      for (int r = 0; r < 4; ++r) of[dt][r] *= alpha[r];

    __syncthreads();

    // O += P V
#pragma unroll
    for (int kk = 0; kk < 2; ++kk) {
      bf16x8 pf = *(const bf16x8*)(p_lds + wave * 1152 + l15 * 72 + kk * 32 + quad * 8);
#pragma unroll
      for (int dt = 0; dt < 4; ++dt) {
        bf16x8 vf = *(const bf16x8*)(vt_lds + (dt * 16 + l15) * 72 + kk * 32 + quad * 8);
        of[dt] = MFMA_16x16x32(pf, vf, of[dt]);
      }
    }
  }

  float inv[4];
#pragma unroll
  for (int r = 0; r < 4; ++r) inv[r] = 1.0f / fmaxf(l_i[r], 1e-20f);
  bf16_t* op = qk + ((size_t)(b * 4096 + qw)) * 2048 + h * 64;  // overwrite Q cols
#pragma unroll
  for (int dt = 0; dt < 4; ++dt)
#pragma unroll
    for (int r = 0; r < 4; ++r)
      op[(size_t)(quad * 4 + r) * 2048 + dt * 16 + l15] = (bf16_t)clampf(of[dt][r] * inv[r]);
}

// ---------------------------------------------------------------------------
extern "C" void kernel_launch(void* const* d_in, const int* in_sizes, int n_in,
                              void* d_out, int out_size, void* d_ws, size_t ws_size,
                              hipStream_t stream) {
  char* ws = (char*)d_ws;
  bf16_t* wTq = (bf16_t*)(ws);                    // [3072][1024]   6,291,456 B
  bf16_t* wTo = (bf16_t*)(ws + 6291456);          // [1024][1024]   2,097,152 B
  bf16_t* qkb = (bf16_t*)(ws + 8388608);          // [16384][2048] 67,108,864 B
  bf16_t* vTb = (bf16_t*)(ws + 75497472);         // [4][16][64][4096] 33,554,432 B
  int* flag = (int*)(ws + 109051904);             // 4 B  (total 109,051,908 B)

  bf16_t* xb = (bf16_t*)d_out;   // converted x staged in d_out (exactly 32 MB),
                                 // fully consumed before the final GEMM writes.
  bf16_t* tmpq = qkb;            // converted w_qkv, consumed by transpose
  bf16_t* tmpo = qkb + 3145728;  // converted w_out, consumed by transpose

  detect_dtype<<<1, 256, 0, stream>>>((const ushort_t*)d_in[0], flag);
  convert_to_bf16<<<1024, 256, 0, stream>>>(d_in[0], xb, 2097152, flag);
  convert_to_bf16<<<512, 256, 0, stream>>>(d_in[1], tmpq, 393216, flag);
  convert_to_bf16<<<256, 256, 0, stream>>>(d_in[2], tmpo, 131072, flag);
  transpose_b16<<<dim3(48, 16), 256, 0, stream>>>((const ushort_t*)tmpq, (ushort_t*)wTq,
                                                  1024, 3072);
  transpose_b16<<<dim3(16, 16), 256, 0, stream>>>((const ushort_t*)tmpo, (ushort_t*)wTo,
                                                  1024, 1024);
  gemm_bf16<1><<<dim3(24, 128), 256, 0, stream>>>(xb, 1024, wTq, nullptr, 0, qkb, vTb,
                                                  16384, 1024, nullptr);
  attn_swa<<<dim3(4096), 256, 0, stream>>>(qkb, vTb);
  gemm_bf16<0><<<dim3(8, 128), 256, 0, stream>>>(qkb, 2048, wTo, d_out, 1024, nullptr,
                                                 nullptr, 16384, 1024, flag);
}

// Round 4
// 432.573 us; speedup vs baseline: 1.9009x; 1.9009x over previous
//
#include <hip/hip_runtime.h>

typedef __bf16 bf16_t;
typedef __bf16 bf16x8 __attribute__((ext_vector_type(8)));
typedef float f32x4 __attribute__((ext_vector_type(4)));
typedef unsigned short ushort_t;

#define MFMA_16x16x32(a, b, c) __builtin_amdgcn_mfma_f32_16x16x32_bf16((a), (b), (c), 0, 0, 0)

// async global->LDS, 16B per lane. LDS dest must be wave-uniform; HW adds lane*16.
__device__ __forceinline__ void async_ld16(const void* gptr, void* lptr) {
  typedef __attribute__((address_space(1))) const unsigned int as1_t;
  typedef __attribute__((address_space(3))) unsigned int as3_t;
  __builtin_amdgcn_global_load_lds((as1_t*)(unsigned long long)gptr,
                                   (as3_t*)(unsigned int)(unsigned long long)lptr,
                                   16, 0, 0);
}

// ---------------------------------------------------------------------------
// Input-dtype detector (f32-read-as-bf16 has ~47% wild exponents in low halves).
// ---------------------------------------------------------------------------
__global__ void detect_dtype(const ushort_t* __restrict__ x, int* __restrict__ flag) {
  __shared__ int cnt[256];
  int c = 0;
#pragma unroll
  for (int i = 0; i < 16; ++i) {
    const ushort_t u = x[threadIdx.x * 16 + i];
    const int e = (u >> 7) & 0xFF;
    if ((u & 0x7FFF) != 0 && (e < 0x3A || e > 0xC0)) ++c;
  }
  cnt[threadIdx.x] = c;
  __syncthreads();
  if (threadIdx.x == 0) {
    int t = 0;
    for (int i = 0; i < 256; ++i) t += cnt[i];
    *flag = (t > 512) ? 1 : 0;
  }
}

// ---------------------------------------------------------------------------
// Normalize input to bf16 (flag==1: f32 src; else 16B copy). n8 = elems/8.
// ---------------------------------------------------------------------------
__global__ __launch_bounds__(256) void convert_to_bf16(const void* __restrict__ src,
                                                       bf16_t* __restrict__ dst, int n8,
                                                       const int* __restrict__ flag) {
  const int isF32 = *flag;
  int i = blockIdx.x * 256 + threadIdx.x;
  const int stride = gridDim.x * 256;
  if (isF32) {
    const float4* s = (const float4*)src;
    for (; i < n8; i += stride) {
      const float4 a = s[(size_t)i * 2];
      const float4 b = s[(size_t)i * 2 + 1];
      bf16x8 o;
      o[0] = (bf16_t)a.x; o[1] = (bf16_t)a.y; o[2] = (bf16_t)a.z; o[3] = (bf16_t)a.w;
      o[4] = (bf16_t)b.x; o[5] = (bf16_t)b.y; o[6] = (bf16_t)b.z; o[7] = (bf16_t)b.w;
      *(bf16x8*)(dst + (size_t)i * 8) = o;
    }
  } else {
    const uint4* s = (const uint4*)src;
    for (; i < n8; i += stride) ((uint4*)dst)[i] = s[i];
  }
}

// ---------------------------------------------------------------------------
// 64x64 bf16 transpose: out[c][r] = in[r][c].  R,C multiples of 64.
// ---------------------------------------------------------------------------
__global__ __launch_bounds__(256) void transpose_b16(const ushort_t* __restrict__ in,
                                                     ushort_t* __restrict__ out,
                                                     int R, int C) {
  __shared__ alignas(16) ushort_t t[64 * 72];
  const int tid = threadIdx.x;
  const int c0 = blockIdx.x * 64;
  const int r0 = blockIdx.y * 64;
#pragma unroll
  for (int it = 0; it < 2; ++it) {
    int cid = tid + it * 256;
    int row = cid >> 3, co = (cid & 7) * 8;
    *(uint4*)(t + row * 72 + co) = *(const uint4*)(in + (size_t)(r0 + row) * C + c0 + co);
  }
  __syncthreads();
#pragma unroll
  for (int it = 0; it < 2; ++it) {
    int cid = tid + it * 256;
    int orow = cid >> 3, ko = (cid & 7) * 8;
    uint4 u;
    ushort_t* tp = (ushort_t*)&u;
#pragma unroll
    for (int j = 0; j < 8; ++j) tp[j] = t[(ko + j) * 72 + orow];
    *(uint4*)(out + (size_t)(c0 + orow) * R + r0 + ko) = u;
  }
}

// ---------------------------------------------------------------------------
// Batched V transpose: qkv[b*4096+l][2048+h*64+d] -> vT[((b*16+h)*64+d)*4096+l]
// grid (64 l-tiles, 64 bh). Fully coalesced 16B both sides.
// ---------------------------------------------------------------------------
__global__ __launch_bounds__(256) void transpose_v(const ushort_t* __restrict__ qkv,
                                                   ushort_t* __restrict__ vT) {
  __shared__ alignas(16) ushort_t t[64 * 72];
  const int tid = threadIdx.x;
  const int l0 = blockIdx.x * 64;
  const int bh = blockIdx.y;
  const int b = bh >> 4, h = bh & 15;
  const ushort_t* src = qkv + ((size_t)(b * 4096 + l0)) * 3072 + 2048 + h * 64;
#pragma unroll
  for (int it = 0; it < 2; ++it) {
    int cid = tid + it * 256;
    int row = cid >> 3, co = (cid & 7) * 8;
    *(uint4*)(t + row * 72 + co) = *(const uint4*)(src + (size_t)row * 3072 + co);
  }
  __syncthreads();
  ushort_t* dst = vT + ((size_t)bh * 64) * 4096 + l0;
#pragma unroll
  for (int it = 0; it < 2; ++it) {
    int cid = tid + it * 256;
    int d = cid >> 3, ko = (cid & 7) * 8;
    uint4 u;
    ushort_t* tp = (ushort_t*)&u;
#pragma unroll
    for (int j = 0; j < 8; ++j) tp[j] = t[(ko + j) * 72 + d];
    *(uint4*)(dst + (size_t)d * 4096 + ko) = u;
  }
}

// ---------------------------------------------------------------------------
// GEMM: C[M][N] = A[M][K] * Bt[N][K]^T. 128x128 tile, 4 waves 64x64, BK=32,
// async global_load_lds staging (m97 structure). Epilogue: bf16 path shuffles
// the C-fragment through LDS into 16B/lane coalesced stores; f32 path (flag)
// stores direct (already 64B/quad-row coalesced).
// ---------------------------------------------------------------------------
__global__ __launch_bounds__(256) void gemm_bf16(const bf16_t* __restrict__ A, int lda,
                                                 const bf16_t* __restrict__ Bt,
                                                 void* __restrict__ Cout, int N_out,
                                                 int K, const int* __restrict__ flag) {
  __shared__ alignas(16) bf16_t smem[8192];  // A tile [0,4096), B tile [4096,8192)
  bf16_t* a_lds = smem;
  bf16_t* b_lds = smem + 4096;
  const int tid = threadIdx.x;
  const int wave = tid >> 6;
  const int lane = tid & 63;
  const int l15 = lane & 15;
  const int quad = lane >> 4;
  const int tm = blockIdx.y * 128;
  const int tn = blockIdx.x * 128;
  const int wm = (wave >> 1) * 64;
  const int wn = (wave & 1) * 64;

  f32x4 acc[4][4];
#pragma unroll
  for (int i = 0; i < 4; ++i)
#pragma unroll
    for (int j = 0; j < 4; ++j) acc[i][j] = (f32x4){0.f, 0.f, 0.f, 0.f};

  // staging: wave stages rows [wave*32, wave*32+32); lane's slot = base + lane*16B
  const int srow = wave * 32 + (lane >> 2);
  const int scol = (lane & 3) * 8;
  const bf16_t* ag = A + (size_t)(tm + srow) * lda + scol;
  const bf16_t* bg = Bt + (size_t)(tn + srow) * K + scol;
  bf16_t* al = a_lds + (wave * 32) * 32;  // wave-uniform
  bf16_t* bl = b_lds + (wave * 32) * 32;

  for (int k0 = 0; k0 < K; k0 += 32) {
    __syncthreads();
    async_ld16(ag, al);
    async_ld16(ag + (size_t)16 * lda, al + 16 * 32);
    async_ld16(bg, bl);
    async_ld16(bg + (size_t)16 * K, bl + 16 * 32);
    ag += 32;
    bg += 32;
    __syncthreads();

    bf16x8 af[4], bfr[4];
#pragma unroll
    for (int i = 0; i < 4; ++i)
      af[i] = *(const bf16x8*)(a_lds + (wm + i * 16 + l15) * 32 + quad * 8);
#pragma unroll
    for (int j = 0; j < 4; ++j)
      bfr[j] = *(const bf16x8*)(b_lds + (wn + j * 16 + l15) * 32 + quad * 8);
#pragma unroll
    for (int i = 0; i < 4; ++i)
#pragma unroll
      for (int j = 0; j < 4; ++j) acc[i][j] = MFMA_16x16x32(af[i], bfr[j], acc[i][j]);
  }
  __syncthreads();  // all MFMA LDS reads done; smem is reusable for epilogue

  const int isF32 = flag ? *flag : 0;
  if (isF32) {
#pragma unroll
    for (int i = 0; i < 4; ++i) {
      const int m = tm + wm + i * 16 + quad * 4;
#pragma unroll
      for (int j = 0; j < 4; ++j) {
        const int n = tn + wn + j * 16 + l15;
        float* cp = (float*)Cout + (size_t)m * N_out + n;
#pragma unroll
        for (int r = 0; r < 4; ++r) cp[(size_t)r * N_out] = acc[i][j][r];
      }
    }
  } else {
    // per-wave 16x72 staging tile; shuffle C-layout -> row-major 16B chunks
    bf16_t* stg = smem + wave * 1152;
#pragma unroll
    for (int i = 0; i < 4; ++i) {
#pragma unroll
      for (int j = 0; j < 4; ++j)
#pragma unroll
        for (int r = 0; r < 4; ++r)
          stg[(quad * 4 + r) * 72 + j * 16 + l15] = (bf16_t)acc[i][j][r];
      __asm__ volatile("s_waitcnt lgkmcnt(0)" ::: "memory");
      const int m0 = tm + wm + i * 16;
#pragma unroll
      for (int p = 0; p < 2; ++p) {
        const int idx = lane + p * 64;
        const int row = idx >> 3, c8 = (idx & 7) * 8;
        uint4 u = *(const uint4*)(stg + row * 72 + c8);
        *(uint4*)((bf16_t*)Cout + (size_t)(m0 + row) * N_out + tn + wn + c8) = u;
      }
      __asm__ volatile("s_waitcnt lgkmcnt(0)" ::: "memory");
    }
  }
}

// ---------------------------------------------------------------------------
// Sliding-window attention. One workgroup = 64 queries of one (b,h); 4 waves x
// 16 rows. Window = 5 chunks of 64 keys. qkv: [b*4096+pos][3072] (Q at h*64,
// K at 1024+h*64; O overwrites the Q columns). vT: [b][h][d][4096].
// ---------------------------------------------------------------------------
__global__ __launch_bounds__(256) void attn_swa(bf16_t* qkv, const bf16_t* __restrict__ vT) {
  __shared__ alignas(16) bf16_t k_lds[64 * 72];   // [key][d]
  __shared__ alignas(16) bf16_t vt_lds[64 * 72];  // [d][key]
  __shared__ alignas(16) bf16_t p_lds[4 * 16 * 72];

  const int wg = blockIdx.x;
  const int b = wg >> 10;
  const int h = (wg >> 6) & 15;
  const int qt = wg & 63;
  const int blk = qt >> 2;
  const int wq = qt & 3;
  const int tid = threadIdx.x;
  const int wave = tid >> 6;
  const int lane = tid & 63;
  const int l15 = lane & 15;
  const int quad = lane >> 4;
  const int qw = qt * 64 + wave * 16;

  const size_t qoff = ((size_t)(b * 4096 + qw + l15)) * 3072 + h * 64;
  const bf16x8 qf0 = *(const bf16x8*)(qkv + qoff + quad * 8);
  const bf16x8 qf1 = *(const bf16x8*)(qkv + qoff + 32 + quad * 8);

  f32x4 of[4];
#pragma unroll
  for (int i = 0; i < 4; ++i) of[i] = (f32x4){0.f, 0.f, 0.f, 0.f};
  float m_i[4], l_i[4];
#pragma unroll
  for (int r = 0; r < 4; ++r) {
    m_i[r] = -1e30f;
    l_i[r] = 0.0f;
  }

  const int kb0 = blk * 256 - 256;
  const int kclo = (blk == 0) ? 4 : wq;
  const int kchi = wq + 4;

  for (int kc = kclo; kc <= kchi; ++kc) {
    const int kb = kb0 + kc * 64;
    __syncthreads();
#pragma unroll
    for (int it = 0; it < 2; ++it) {
      int cid = tid + it * 256;
      int row = cid >> 3;
      int co = (cid & 7) * 8;
      *(uint4*)(k_lds + row * 72 + co) =
          *(const uint4*)(qkv + ((size_t)(b * 4096 + kb + row)) * 3072 + 1024 + h * 64 + co);
      *(uint4*)(vt_lds + row * 72 + co) =
          *(const uint4*)(vT + (((size_t)b * 16 + h) * 64 + row) * 4096 + kb + co);
    }
    __syncthreads();

    f32x4 s[4];
#pragma unroll
    for (int nt = 0; nt < 4; ++nt) {
      bf16x8 kf0 = *(const bf16x8*)(k_lds + (nt * 16 + l15) * 72 + quad * 8);
      bf16x8 kf1 = *(const bf16x8*)(k_lds + (nt * 16 + l15) * 72 + 32 + quad * 8);
      f32x4 z = (f32x4){0.f, 0.f, 0.f, 0.f};
      z = MFMA_16x16x32(qf0, kf0, z);
      z = MFMA_16x16x32(qf1, kf1, z);
      s[nt] = z;
    }

    float sv[4][4];
#pragma unroll
    for (int nt = 0; nt < 4; ++nt) {
      const int key = kb + nt * 16 + l15;
#pragma unroll
      for (int r = 0; r < 4; ++r) {
        const int p = qw + quad * 4 + r;
        const bool valid = (key <= p) && (key + 256 > p);
        sv[nt][r] = valid ? s[nt][r] * 0.125f : -1e30f;
      }
    }
    float rm[4];
#pragma unroll
    for (int r = 0; r < 4; ++r)
      rm[r] = fmaxf(fmaxf(sv[0][r], sv[1][r]), fmaxf(sv[2][r], sv[3][r]));
#pragma unroll
    for (int off = 1; off < 16; off <<= 1)
#pragma unroll
      for (int r = 0; r < 4; ++r) rm[r] = fmaxf(rm[r], __shfl_xor(rm[r], off));

    float mn[4], alpha[4];
#pragma unroll
    for (int r = 0; r < 4; ++r) {
      mn[r] = fmaxf(m_i[r], rm[r]);
      alpha[r] = __expf(m_i[r] - mn[r]);
      m_i[r] = mn[r];
    }

    float rs[4] = {0.f, 0.f, 0.f, 0.f};
#pragma unroll
    for (int nt = 0; nt < 4; ++nt)
#pragma unroll
      for (int r = 0; r < 4; ++r) {
        const float pv = (sv[nt][r] > -1e29f) ? __expf(sv[nt][r] - mn[r]) : 0.0f;
        rs[r] += pv;
        p_lds[wave * 1152 + (quad * 4 + r) * 72 + nt * 16 + l15] = (bf16_t)pv;
      }
#pragma unroll
    for (int off = 1; off < 16; off <<= 1)
#pragma unroll
      for (int r = 0; r < 4; ++r) rs[r] += __shfl_xor(rs[r], off);
#pragma unroll
    for (int r = 0; r < 4; ++r) l_i[r] = l_i[r] * alpha[r] + rs[r];
#pragma unroll
    for (int dt = 0; dt < 4; ++dt)
#pragma unroll
      for (int r = 0; r < 4; ++r) of[dt][r] *= alpha[r];

    __syncthreads();

#pragma unroll
    for (int kk = 0; kk < 2; ++kk) {
      bf16x8 pf = *(const bf16x8*)(p_lds + wave * 1152 + l15 * 72 + kk * 32 + quad * 8);
#pragma unroll
      for (int dt = 0; dt < 4; ++dt) {
        bf16x8 vf = *(const bf16x8*)(vt_lds + (dt * 16 + l15) * 72 + kk * 32 + quad * 8);
        of[dt] = MFMA_16x16x32(pf, vf, of[dt]);
      }
    }
  }

  float inv[4];
#pragma unroll
  for (int r = 0; r < 4; ++r) inv[r] = 1.0f / fmaxf(l_i[r], 1e-20f);
  bf16_t* op = qkv + ((size_t)(b * 4096 + qw)) * 3072 + h * 64;  // overwrite Q cols
#pragma unroll
  for (int dt = 0; dt < 4; ++dt)
#pragma unroll
    for (int r = 0; r < 4; ++r)
      op[(size_t)(quad * 4 + r) * 3072 + dt * 16 + l15] = (bf16_t)(of[dt][r] * inv[r]);
}

// ---------------------------------------------------------------------------
extern "C" void kernel_launch(void* const* d_in, const int* in_sizes, int n_in,
                              void* d_out, int out_size, void* d_ws, size_t ws_size,
                              hipStream_t stream) {
  char* ws = (char*)d_ws;
  bf16_t* wTq = (bf16_t*)(ws);                    // [3072][1024]   6,291,456 B
  bf16_t* wTo = (bf16_t*)(ws + 6291456);          // [1024][1024]   2,097,152 B
  bf16_t* qkv = (bf16_t*)(ws + 8388608);          // [16384][3072] 100,663,296 B
  int* flag = (int*)(ws + 109051904);             // 4 B (total 109,051,908 B)

  bf16_t* xb = (bf16_t*)d_out;   // converted x (32 MB), consumed by QKV GEMM
  bf16_t* vTb = (bf16_t*)d_out;  // then vT (32 MB), consumed by attention,
                                 // then final GEMM writes d_out. Stream-ordered.
  bf16_t* tmpq = qkv;            // converted w_qkv, consumed by transpose
  bf16_t* tmpo = qkv + 3145728;  // converted w_out, consumed by transpose

  detect_dtype<<<1, 256, 0, stream>>>((const ushort_t*)d_in[0], flag);
  convert_to_bf16<<<1024, 256, 0, stream>>>(d_in[0], xb, 2097152, flag);
  convert_to_bf16<<<512, 256, 0, stream>>>(d_in[1], tmpq, 393216, flag);
  convert_to_bf16<<<256, 256, 0, stream>>>(d_in[2], tmpo, 131072, flag);
  transpose_b16<<<dim3(48, 16), 256, 0, stream>>>((const ushort_t*)tmpq, (ushort_t*)wTq,
                                                  1024, 3072);
  transpose_b16<<<dim3(16, 16), 256, 0, stream>>>((const ushort_t*)tmpo, (ushort_t*)wTo,
                                                  1024, 1024);
  gemm_bf16<<<dim3(24, 128), 256, 0, stream>>>(xb, 1024, wTq, qkv, 3072, 1024, nullptr);
  transpose_v<<<dim3(64, 64), 256, 0, stream>>>((const ushort_t*)qkv, (ushort_t*)vTb);
  attn_swa<<<dim3(4096), 256, 0, stream>>>(qkv, vTb);
  gemm_bf16<<<dim3(8, 128), 256, 0, stream>>>(qkv, 3072, wTo, d_out, 1024, 1024, flag);
}